// Round 7
// baseline (25565.646 us; speedup 1.0000x reference)
//
#include <hip/hip_runtime.h>

typedef _Float16 f16;
typedef _Float16 f16x8 __attribute__((ext_vector_type(8)));
typedef float f32x16 __attribute__((ext_vector_type(16)));

#define HID   512
#define NSTEP 100
#define WMAT  786432      // halfs per packed weight matrix (1536*512)

__device__ __forceinline__ float sigmoid_f(float x) {
  return 1.0f / (1.0f + __expf(-x));
}
__device__ __forceinline__ float tanh_f(float x) {
  float e = __expf(2.0f * x);
  return 1.0f - 2.0f / (e + 1.0f);
}
__device__ __forceinline__ f32x16 mfma16(f16x8 a, f16x8 b, f32x16 c) {
  return __builtin_amdgcn_mfma_f32_32x32x16_f16(a, b, c, 0, 0, 0);
}
__device__ __forceinline__ f32x16 zero16() {
  f32x16 z;
#pragma unroll
  for (int i = 0; i < 16; ++i) z[i] = 0.f;
  return z;
}

// ---- weight pack: fp32 [1536][512] row-major -> B-fragment-packed fp16 ----
// layout [ct(48)][kt(32)][lane(64)][i(8)]:
//   gate = ct*32 + (lane&31), k = kt*16 + (lane>>5)*8 + i
__global__ void pack_weights(const float* __restrict__ W, f16* __restrict__ out) {
  int t = blockIdx.x * 256 + threadIdx.x;
  if (t >= 48 * 32 * 64) return;
  int lane = t & 63;
  int kt   = (t >> 6) & 31;
  int ct   = t >> 11;
  int gate = ct * 32 + (lane & 31);
  int k0   = kt * 16 + (lane >> 5) * 8;
  const float* src = W + gate * HID + k0;
  f16x8 v;
#pragma unroll
  for (int i = 0; i < 8; ++i) v[i] = (f16)src[i];
  *(f16x8*)(out + (size_t)t * 8) = v;
}

// combined biases: [0..1023]=bi+bh (r,z), [1024..1535]=bi_n, [1536..2047]=bh_n
__global__ void pack_bias(const float* __restrict__ bi, const float* __restrict__ bh,
                          float* __restrict__ out) {
  int j = blockIdx.x * 256 + threadIdx.x;
  if (j < 1024)      out[j] = bi[j] + bh[j];
  else if (j < 1536) out[j] = bi[j];
  else if (j < 2048) out[j] = bh[j - 512];
}

// Persistent per-block GRU: 64 batch rows as TWO 32-row tiles sharing every
// B-fragment (halves L2 weight traffic per row). 8 waves (2/SIMD, 256-reg
// budget), each wave owns 64 hidden cols (2 chunks of 32). h single-buffered
// in-place; writes deferred past a barrier in hv regs (32 regs only).
// Layer 1 single-pass (6 accs; x-part folded into epilogue as 9 scalar FMAs).
// Layer 2 two passes with disjoint B-streams: {r,z} then {n}.
// h element (tile,row,k) at LDS byte: tl*32768 + row*1024 + ((2k) ^ ((row&7)<<4))
__global__ __launch_bounds__(512, 2) void gru_fused(
    const float* __restrict__ z,
    const float* __restrict__ w_ih1,   // [1536][3] fp32
    const float* __restrict__ fc_w,    // [3][512]  fp32
    const float* __restrict__ fc_b,    // [3]
    const f16*  __restrict__ Wp,       // packed Whh1 | Wih2 | Whh2
    const float* __restrict__ Bb,      // bias1[2048] | bias2[2048]
    float* __restrict__ out)           // [B][100][3] fp32
{
  __shared__ f16   h1s[2 * 32 * HID];   // 64 KB  [tile][row][col]
  __shared__ f16   h2s[2 * 32 * HID];   // 64 KB
  __shared__ float fcwT[3 * HID];       // 6 KB   pos(k) = (k&7)*64 + (k>>3)
  __shared__ float xsf[64 * 4];         // 1 KB   fp32 x state per global row

  const int tid  = threadIdx.x;
  const int lane = tid & 63;
  const int wv   = tid >> 6;            // 0..7
  const int b0   = blockIdx.x * 64;

  {
    f16x8 z8 = {0, 0, 0, 0, 0, 0, 0, 0};
    for (int i = tid; i < 2 * 32 * HID / 8; i += 512) {
      ((f16x8*)h1s)[i] = z8;
      ((f16x8*)h2s)[i] = z8;
    }
    if (tid < HID) {
      const int pos = ((tid & 7) << 6) + (tid >> 3);
      fcwT[pos]        = fc_w[tid];
      fcwT[512 + pos]  = fc_w[512 + tid];
      fcwT[1024 + pos] = fc_w[1024 + tid];
    }
  }
  __syncthreads();
  if (tid < 64 * 3) {
    const int rr = tid / 3, oo = tid - rr * 3;
    float v = z[(size_t)(b0 + rr) * 6 + 3 + oo];
    xsf[rr * 4 + oo] = v;
    out[(size_t)(b0 + rr) * 300 + oo] = v;     // t = 0 output
  }
  __syncthreads();

  const int colid = lane & 31;
  const int khalf = lane >> 5;
  const int klo   = khalf << 4;
  const int patA  = (colid & 7) << 4;
  const int rbase = colid * 1024;
  const int jw    = wv << 6;            // wave owns cols [jw, jw+64)

  const f16* W1  = Wp;
  const f16* Wi2 = Wp + WMAT;
  const f16* Wh2 = Wp + 2 * WMAT;

  // per-chunk constants (constant over t)
  float b1r[2], b1z[2], b1ni[2], b1nh[2], b2r[2], b2z[2], b2ni[2], b2nh[2];
  float wr0[2], wr1[2], wr2[2], wz0[2], wz1[2], wz2[2], wn0[2], wn1[2], wn2[2];
#pragma unroll
  for (int c = 0; c < 2; ++c) {
    const int j = jw + (c << 5) + colid;
    b1r[c]  = Bb[j];         b1z[c]  = Bb[512 + j];
    b1ni[c] = Bb[1024 + j];  b1nh[c] = Bb[1536 + j];
    b2r[c]  = Bb[2048 + j];         b2z[c]  = Bb[2048 + 512 + j];
    b2ni[c] = Bb[2048 + 1024 + j];  b2nh[c] = Bb[2048 + 1536 + j];
    wr0[c] = w_ih1[j * 3];             wr1[c] = w_ih1[j * 3 + 1];             wr2[c] = w_ih1[j * 3 + 2];
    wz0[c] = w_ih1[(512 + j) * 3];     wz1[c] = w_ih1[(512 + j) * 3 + 1];     wz2[c] = w_ih1[(512 + j) * 3 + 2];
    wn0[c] = w_ih1[(1024 + j) * 3];    wn1[c] = w_ih1[(1024 + j) * 3 + 1];    wn2[c] = w_ih1[(1024 + j) * 3 + 2];
  }
  const float fb0 = fc_b[0], fb1 = fc_b[1], fb2 = fc_b[2];

  for (int t = 1; t < NSTEP; ++t) {
    f16x8 hv[2][2][2];   // deferred h_new: [chunk][tile][half]

    // ================= Layer 1: single pass, 6 accs =================
#pragma unroll
    for (int c = 0; c < 2; ++c) {
      const int ct = (wv << 1) + c;
      f32x16 aR0 = zero16(), aR1 = zero16();
      f32x16 aZ0 = zero16(), aZ1 = zero16();
      f32x16 aN0 = zero16(), aN1 = zero16();
      const f16* Br = W1 + (size_t)ct * 16384 + lane * 8;
      const f16* Bz = W1 + (size_t)(16 + ct) * 16384 + lane * 8;
      const f16* Bn = W1 + (size_t)(32 + ct) * 16384 + lane * 8;
#pragma unroll 2
      for (int kt = 0; kt < 32; ++kt) {
        const int koff = ((kt << 5) | klo) ^ patA;
        f16x8 a0 = *(const f16x8*)((const char*)h1s + rbase + koff);
        f16x8 a1 = *(const f16x8*)((const char*)h1s + 32768 + rbase + koff);
        f16x8 br = *(const f16x8*)(Br + kt * 512);
        f16x8 bz = *(const f16x8*)(Bz + kt * 512);
        f16x8 bn = *(const f16x8*)(Bn + kt * 512);
        aR0 = mfma16(a0, br, aR0);  aR1 = mfma16(a1, br, aR1);
        aZ0 = mfma16(a0, bz, aZ0);  aZ1 = mfma16(a1, bz, aZ1);
        aN0 = mfma16(a0, bn, aN0);  aN1 = mfma16(a1, bn, aN1);
      }
      const int jxc = 2 * (jw + (c << 5) + colid);
#pragma unroll
      for (int tl = 0; tl < 2; ++tl) {
        const f32x16 aR = tl ? aR1 : aR0;
        const f32x16 aZ = tl ? aZ1 : aZ0;
        const f32x16 aN = tl ? aN1 : aN0;
#pragma unroll
        for (int qq = 0; qq < 16; ++qq) {
          const int row = (qq & 3) + ((qq >> 2) << 3) + (khalf << 2);
          const float4 xv = *(const float4*)(xsf + ((tl << 5) + row) * 4);
          const float gir = fmaf(xv.x, wr0[c], fmaf(xv.y, wr1[c], xv.z * wr2[c]));
          const float giz = fmaf(xv.x, wz0[c], fmaf(xv.y, wz1[c], xv.z * wz2[c]));
          const float gin = fmaf(xv.x, wn0[c], fmaf(xv.y, wn1[c], xv.z * wn2[c]));
          float r  = sigmoid_f(aR[qq] + gir + b1r[c]);
          float zt = sigmoid_f(aZ[qq] + giz + b1z[c]);
          float n  = tanh_f(gin + b1ni[c] + r * (aN[qq] + b1nh[c]));
          float hold = (float)*(const f16*)((const char*)h1s + tl * 32768 + row * 1024 + (jxc ^ ((row & 7) << 4)));
          hv[c][tl][qq >> 3][qq & 7] = (f16)((1.0f - zt) * n + zt * hold);
        }
      }
    }
    __syncthreads();
#pragma unroll
    for (int c = 0; c < 2; ++c) {
      const int jxc = 2 * (jw + (c << 5) + colid);
#pragma unroll
      for (int tl = 0; tl < 2; ++tl)
#pragma unroll
        for (int qq = 0; qq < 16; ++qq) {
          const int row = (qq & 3) + ((qq >> 2) << 3) + (khalf << 2);
          *(f16*)((char*)h1s + tl * 32768 + row * 1024 + (jxc ^ ((row & 7) << 4))) = hv[c][tl][qq >> 3][qq & 7];
        }
    }
    __syncthreads();

    // ================= Layer 2: pass 1 {r,z}, pass 2 {n} =================
#pragma unroll
    for (int c = 0; c < 2; ++c) {
      const int ct = (wv << 1) + c;
      f16x8 rv[2][2], zv[2][2];
      {
        f32x16 aR0 = zero16(), aR1 = zero16();
        f32x16 aZ0 = zero16(), aZ1 = zero16();
        const f16* Bir = Wi2 + (size_t)ct * 16384 + lane * 8;
        const f16* Biz = Wi2 + (size_t)(16 + ct) * 16384 + lane * 8;
        const f16* Bhr = Wh2 + (size_t)ct * 16384 + lane * 8;
        const f16* Bhz = Wh2 + (size_t)(16 + ct) * 16384 + lane * 8;
#pragma unroll 2
        for (int kt = 0; kt < 32; ++kt) {
          const int koff = ((kt << 5) | klo) ^ patA;
          f16x8 a10 = *(const f16x8*)((const char*)h1s + rbase + koff);
          f16x8 a11 = *(const f16x8*)((const char*)h1s + 32768 + rbase + koff);
          f16x8 a20 = *(const f16x8*)((const char*)h2s + rbase + koff);
          f16x8 a21 = *(const f16x8*)((const char*)h2s + 32768 + rbase + koff);
          f16x8 bir = *(const f16x8*)(Bir + kt * 512);
          f16x8 bhr = *(const f16x8*)(Bhr + kt * 512);
          f16x8 biz = *(const f16x8*)(Biz + kt * 512);
          f16x8 bhz = *(const f16x8*)(Bhz + kt * 512);
          aR0 = mfma16(a10, bir, aR0);  aR0 = mfma16(a20, bhr, aR0);
          aR1 = mfma16(a11, bir, aR1);  aR1 = mfma16(a21, bhr, aR1);
          aZ0 = mfma16(a10, biz, aZ0);  aZ0 = mfma16(a20, bhz, aZ0);
          aZ1 = mfma16(a11, biz, aZ1);  aZ1 = mfma16(a21, bhz, aZ1);
        }
#pragma unroll
        for (int tl = 0; tl < 2; ++tl) {
          const f32x16 aR = tl ? aR1 : aR0;
          const f32x16 aZ = tl ? aZ1 : aZ0;
#pragma unroll
          for (int qq = 0; qq < 16; ++qq) {
            rv[tl][qq >> 3][qq & 7] = (f16)sigmoid_f(aR[qq] + b2r[c]);
            zv[tl][qq >> 3][qq & 7] = (f16)sigmoid_f(aZ[qq] + b2z[c]);
          }
        }
      }
      {
        f32x16 aI0 = zero16(), aI1 = zero16();
        f32x16 aH0 = zero16(), aH1 = zero16();
        const f16* Bin = Wi2 + (size_t)(32 + ct) * 16384 + lane * 8;
        const f16* Bhn = Wh2 + (size_t)(32 + ct) * 16384 + lane * 8;
#pragma unroll 2
        for (int kt = 0; kt < 32; ++kt) {
          const int koff = ((kt << 5) | klo) ^ patA;
          f16x8 a10 = *(const f16x8*)((const char*)h1s + rbase + koff);
          f16x8 a11 = *(const f16x8*)((const char*)h1s + 32768 + rbase + koff);
          f16x8 a20 = *(const f16x8*)((const char*)h2s + rbase + koff);
          f16x8 a21 = *(const f16x8*)((const char*)h2s + 32768 + rbase + koff);
          f16x8 bin8 = *(const f16x8*)(Bin + kt * 512);
          f16x8 bhn8 = *(const f16x8*)(Bhn + kt * 512);
          aI0 = mfma16(a10, bin8, aI0);  aI1 = mfma16(a11, bin8, aI1);
          aH0 = mfma16(a20, bhn8, aH0);  aH1 = mfma16(a21, bhn8, aH1);
        }
        const int jxc = 2 * (jw + (c << 5) + colid);
#pragma unroll
        for (int tl = 0; tl < 2; ++tl) {
          const f32x16 aI = tl ? aI1 : aI0;
          const f32x16 aH = tl ? aH1 : aH0;
#pragma unroll
          for (int qq = 0; qq < 16; ++qq) {
            const int row = (qq & 3) + ((qq >> 2) << 3) + (khalf << 2);
            float r  = (float)rv[tl][qq >> 3][qq & 7];
            float zt = (float)zv[tl][qq >> 3][qq & 7];
            float n  = tanh_f(aI[qq] + b2ni[c] + r * (aH[qq] + b2nh[c]));
            float hold = (float)*(const f16*)((const char*)h2s + tl * 32768 + row * 1024 + (jxc ^ ((row & 7) << 4)));
            hv[c][tl][qq >> 3][qq & 7] = (f16)((1.0f - zt) * n + zt * hold);
          }
        }
      }
    }
    __syncthreads();
#pragma unroll
    for (int c = 0; c < 2; ++c) {
      const int jxc = 2 * (jw + (c << 5) + colid);
#pragma unroll
      for (int tl = 0; tl < 2; ++tl)
#pragma unroll
        for (int qq = 0; qq < 16; ++qq) {
          const int row = (qq & 3) + ((qq >> 2) << 3) + (khalf << 2);
          *(f16*)((char*)h2s + tl * 32768 + row * 1024 + (jxc ^ ((row & 7) << 4))) = hv[c][tl][qq >> 3][qq & 7];
        }
    }
    __syncthreads();

    // ================= FC head: 8 waves x 8 rows, 8-lane shuffle reduce =================
    {
      const int rowg = (wv << 3) + (lane >> 3);   // global row 0..63
      const int tl   = rowg >> 5;
      const int rit  = rowg & 31;
      const int sl   = lane & 7;                  // k-slice of 64
      const char* hb = (const char*)h2s + tl * 32768 + rit * 1024;
      const int pat = (rit & 7) << 4;
      float p0 = 0.f, p1 = 0.f, p2 = 0.f;
#pragma unroll
      for (int j = 0; j < 8; ++j) {
        f16x8 hh = *(const f16x8*)(hb + (((sl << 7) | (j << 4)) ^ pat));
#pragma unroll
        for (int i = 0; i < 8; ++i) {
          const float hf = (float)hh[i];
          const int pos = (i << 6) + (sl << 3) + j;
          p0 = fmaf(hf, fcwT[pos], p0);
          p1 = fmaf(hf, fcwT[512 + pos], p1);
          p2 = fmaf(hf, fcwT[1024 + pos], p2);
        }
      }
#pragma unroll
      for (int m = 1; m < 8; m <<= 1) {
        p0 += __shfl_xor(p0, m, 64);
        p1 += __shfl_xor(p1, m, 64);
        p2 += __shfl_xor(p2, m, 64);
      }
      if (sl == 0) {
        float x0 = xsf[(rowg << 2) + 0] + 0.1f * tanh_f(p0 + fb0);
        float x1 = xsf[(rowg << 2) + 1] + 0.1f * tanh_f(p1 + fb1);
        float x2 = xsf[(rowg << 2) + 2] + 0.1f * tanh_f(p2 + fb2);
        xsf[(rowg << 2) + 0] = x0;
        xsf[(rowg << 2) + 1] = x1;
        xsf[(rowg << 2) + 2] = x2;
        float* op = out + (size_t)(b0 + rowg) * 300 + (size_t)t * 3;
        op[0] = x0; op[1] = x1; op[2] = x2;
      }
    }
    __syncthreads();
  }
}

extern "C" void kernel_launch(void* const* d_in, const int* in_sizes, int n_in,
                              void* d_out, int out_size, void* d_ws, size_t ws_size,
                              hipStream_t stream) {
  const float* z     = (const float*)d_in[0];
  const float* w_ih1 = (const float*)d_in[1];
  const float* w_hh1 = (const float*)d_in[2];
  const float* b_ih1 = (const float*)d_in[3];
  const float* b_hh1 = (const float*)d_in[4];
  const float* w_ih2 = (const float*)d_in[5];
  const float* w_hh2 = (const float*)d_in[6];
  const float* b_ih2 = (const float*)d_in[7];
  const float* b_hh2 = (const float*)d_in[8];
  const float* fc_w  = (const float*)d_in[9];
  const float* fc_b  = (const float*)d_in[10];
  float* out = (float*)d_out;

  f16*   Wp = (f16*)d_ws;                                          // 3 * 1.5 MB packed fp16
  float* Bb = (float*)((char*)d_ws + (size_t)3 * WMAT * 2);

  const int nbatch = in_sizes[0] / 6;

  pack_weights<<<384, 256, 0, stream>>>(w_hh1, Wp);
  pack_weights<<<384, 256, 0, stream>>>(w_ih2, Wp + WMAT);
  pack_weights<<<384, 256, 0, stream>>>(w_hh2, Wp + 2 * WMAT);
  pack_bias<<<8, 256, 0, stream>>>(b_ih1, b_hh1, Bb);
  pack_bias<<<8, 256, 0, stream>>>(b_ih2, b_hh2, Bb + 2048);

  gru_fused<<<nbatch / 64, 512, 0, stream>>>(z, w_ih1, fc_w, fc_b, Wp, Bb, out);
}